// Round 10
// baseline (51.431 us; speedup 1.0000x reference)
//
#include <hip/hip_runtime.h>

// LiftSplatShoot: frustum geometry -> voxel scatter-add.
// f64 geometry (matches numpy f64 ref). Pipeline:
//   k0 (init): zero 41MB scratch + zero 20KB touched-bitmap + per-(b,n)
//              matrix precompute -> ws   (all state re-zeroed EVERY call;
//              nothing persists across graph replays)
//   k1 (scatter): one wave per (b,n,d,w); lanes = channels. Lanes 0..15
//              compute f64 transform for h=lane -> voxel addr. Register
//              run-length merge -> coalesced 64-lane atomic bursts into
//              channel-fast scratch(b,v,c); lane 0 marks bitmap per burst.
//   k2 (transpose): LDS 64x64 tile, scratch(b,v,c) -> out(b,c,v); bitmap
//              gates scratch reads (untouched rows -> 0.0 without reading);
//              fully-untouched tiles write float4 zeros directly.
// Fallback (small ws): direct strided atomics into out.

#define FHH 16
#define FWW 44
#define NDD 41
#define NCAM 6
#define NB 4
#define NC 64
#define NX0 200
#define NX1 200
#define NVOX (NX0*NX1)
#define NBM_WORDS (NB*NVOX/32)            // 5000 uint32 = 20 KB
#define BITMAP_OFF_BYTES 8192
#define SCRATCH_OFF_BYTES 32768
#define NXCD 8
#define SCATTER_BLOCKS (NB*NCAM*NDD*11)   // 10824 = 8 * 1353
#define ZERO_BLOCKS 2500   // 2500 * 256 threads * 4 float4 = 10.24M floats

// 3x3 inverse in double: LU with partial pivoting + triangular solves.
__device__ void lu_inv3d(const double A[3][3], double out[3][3]) {
  double M[3][3]; int piv[3] = {0,1,2};
  for (int i=0;i<3;i++) for (int j=0;j<3;j++) M[i][j]=A[i][j];
  for (int k=0;k<3;k++){
    int p=k; double mx=fabs(M[k][k]);
    for (int r=k+1;r<3;r++){ double v=fabs(M[r][k]); if (v>mx){mx=v;p=r;} }
    if (p!=k){
      for (int j=0;j<3;j++){ double t=M[k][j]; M[k][j]=M[p][j]; M[p][j]=t; }
      int t=piv[k]; piv[k]=piv[p]; piv[p]=t;
    }
    for (int r=k+1;r<3;r++){
      double l = M[r][k] / M[k][k];
      M[r][k]=l;
      for (int j=k+1;j<3;j++) M[r][j] -= l*M[k][j];
    }
  }
  for (int col=0; col<3; col++){
    double bb[3];
    for (int i=0;i<3;i++) bb[i] = (piv[i]==col) ? 1.0 : 0.0;
    for (int i=1;i<3;i++){
      double acc=bb[i];
      for (int j=0;j<i;j++) acc -= M[i][j]*bb[j];
      bb[i]=acc;
    }
    for (int i=2;i>=0;i--){
      double acc=bb[i];
      for (int j=i+1;j<3;j++) acc -= M[i][j]*bb[j];
      bb[i]=acc / M[i][i];
    }
    out[0][col]=bb[0]; out[1][col]=bb[1]; out[2][col]=bb[2];
  }
}

// ws layout per bn (24 doubles): C[9], iPR[9], T[3], P[3]
__device__ void precompute_bn(
    const float* __restrict__ rots, const float* __restrict__ intrins,
    const float* __restrict__ post_rots, const float* __restrict__ trans,
    const float* __restrict__ post_trans, double* __restrict__ ws, int bn)
{
  double R[3][3], K[3][3], PR[3][3];
  for (int i=0;i<3;i++) for (int j=0;j<3;j++){
    R[i][j]=(double)rots[bn*9+i*3+j];
    K[i][j]=(double)intrins[bn*9+i*3+j];
    PR[i][j]=(double)post_rots[bn*9+i*3+j];
  }
  double iK[3][3], iPR[3][3];
  lu_inv3d(K, iK);
  lu_inv3d(PR, iPR);
  double* W = ws + bn*24;
  for (int i=0;i<3;i++) for (int j=0;j<3;j++){
    W[i*3+j]   = R[i][0]*iK[0][j] + R[i][1]*iK[1][j] + R[i][2]*iK[2][j];
    W[9+i*3+j] = iPR[i][j];
  }
  for (int i=0;i<3;i++){
    W[18+i] = (double)trans[bn*3+i];
    W[21+i] = (double)post_trans[bn*3+i];
  }
}

// k0: zero scratch + zero bitmap + precompute matrices (one launch)
__global__ __launch_bounds__(256) void lss_init_kernel(
    const float* __restrict__ rots, const float* __restrict__ intrins,
    const float* __restrict__ post_rots, const float* __restrict__ trans,
    const float* __restrict__ post_trans,
    float* __restrict__ scratch, unsigned int* __restrict__ bitmap,
    double* __restrict__ ws)
{
  const int blk = (int)blockIdx.x;
  if (blk < ZERO_BLOCKS) {
    float4 z; z.x=0.f; z.y=0.f; z.z=0.f; z.w=0.f;
    float4* p = (float4*)scratch + (size_t)blk*1024;
    const int t = threadIdx.x;
    p[t] = z; p[t+256] = z; p[t+512] = z; p[t+768] = z;
  } else if (blk < ZERO_BLOCKS + 20) {
    const int idx = (blk - ZERO_BLOCKS)*256 + (int)threadIdx.x;
    if (idx < NBM_WORDS) bitmap[idx] = 0u;
  } else {
    const int bn = threadIdx.x;
    if (bn < NB*NCAM)
      precompute_bn(rots, intrins, post_rots, trans, post_trans, ws, bn);
  }
}

// standalone precompute (fallback path)
__global__ __launch_bounds__(64) void lss_precompute_kernel(
    const float* __restrict__ rots, const float* __restrict__ intrins,
    const float* __restrict__ post_rots, const float* __restrict__ trans,
    const float* __restrict__ post_trans, double* __restrict__ ws)
{
  const int bn = threadIdx.x;
  if (bn < NB*NCAM)
    precompute_bn(rots, intrins, post_rots, trans, post_trans, ws, bn);
}

// Spatial voxel index b*NVOX + iy*NX0+ix for h=lane (lanes 0..15), else -1.
__device__ __forceinline__ int voxel_addr_for_lane(
    const double* __restrict__ ws, int bn, int b, int d, int w, int lane)
{
  if (lane >= FHH) return -1;
  const double* W = ws + bn*24;
  const double u  = (double)w * (703.0/43.0);
  const double v  = (double)lane * 17.0;
  const double dd = (double)(4 + d);
  const double p0x = u  - W[21];
  const double p0y = v  - W[22];
  const double p0z = dd - W[23];
  const double p1x = W[9+0]*p0x + W[9+1]*p0y + W[9+2]*p0z;
  const double p1y = W[9+3]*p0x + W[9+4]*p0y + W[9+5]*p0z;
  const double p1z = W[9+6]*p0x + W[9+7]*p0y + W[9+8]*p0z;
  const double p2x = p1x * p1z;
  const double p2y = p1y * p1z;
  const double p2z = p1z;
  const double gx = W[0]*p2x + W[1]*p2y + W[2]*p2z + W[18];
  const double gy = W[3]*p2x + W[4]*p2y + W[5]*p2z + W[19];
  const double gz = W[6]*p2x + W[7]*p2y + W[8]*p2z + W[20];
  const double tx = (gx + 50.0) / 0.5;
  const double ty = (gy + 50.0) / 0.5;
  const double tz = (gz + 10.0) / 20.0;
  const int ix = (int)tx;
  const int iy = (int)ty;
  const int iz = (int)tz;
  const bool kept = (ix>=0) && (ix<NX0) && (iy>=0) && (iy<NX1) && (iz==0);
  return kept ? ((b*NX1 + iy)*NX0 + ix) : -1;
}

// k1: scatter into channel-fast scratch: scratch[(vox<<6)+c]; mark bitmap.
__global__ __launch_bounds__(256) void lss_scatter_cf_kernel(
    const float* __restrict__ x_img, const double* __restrict__ ws,
    float* __restrict__ scratch, unsigned int* __restrict__ bitmap)
{
  // XCD-chunked bijective swizzle (neutral on bench, harmless).
  const int bid = (int)((blockIdx.x % NXCD) * (SCATTER_BLOCKS/NXCD)
                        + blockIdx.x / NXCD);
  const int slab = bid / 11;
  const int sub  = bid % 11;
  const int t = sub*256 + (int)threadIdx.x;
  const int w = t >> 6;
  const int c = t & 63;
  const int b = slab / (NCAM*NDD);
  const int rem = slab % (NCAM*NDD);
  const int n = rem / NDD;
  const int d = rem % NDD;
  const int bn = b*NCAM + n;

  const int myAddr = voxel_addr_for_lane(ws, bn, b, d, w, c);
  const unsigned long long keptMask = __ballot(myAddr >= 0);
  if (keptMask == 0ull) return;

  const float* featbase = x_img + (size_t)(((size_t)bn*NDD + d)*FHH*FWW)*NC
                        + ((size_t)w << 6) + c;

  // loads gated per-h by wave-uniform mask bit (scalar branch, pipelined)
  float f[FHH];
  #pragma unroll
  for (int h=0; h<FHH; h++)
    if (keptMask & (1ull<<h))
      f[h] = featbase[(size_t)h * (FWW*NC)];

  int prevAddr = -1;
  float acc = 0.0f;
  #pragma unroll
  for (int h=0; h<FHH; h++){
    const int a = __shfl(myAddr, h, 64);
    if (a != prevAddr){
      if (prevAddr >= 0){
        atomicAdd(scratch + (((size_t)prevAddr)<<6) + c, acc);
        if (c == 0)
          atomicOr(bitmap + (prevAddr >> 5), 1u << (prevAddr & 31));
      }
      acc = 0.0f;
      prevAddr = a;
    }
    if (a >= 0) acc += f[h];
  }
  if (prevAddr >= 0){
    atomicAdd(scratch + (((size_t)prevAddr)<<6) + c, acc);
    if (c == 0)
      atomicOr(bitmap + (prevAddr >> 5), 1u << (prevAddr & 31));
  }
}

// k2: transpose scratch (b, v, c) -> out (b, c, v); bitmap-gated reads.
__global__ __launch_bounds__(256) void lss_transpose_kernel(
    const float* __restrict__ scratch, const unsigned int* __restrict__ bitmap,
    float* __restrict__ out)
{
  __shared__ float tile[64][65];
  const int tileIdx = blockIdx.x;            // 0..(4*625-1)
  const int b  = tileIdx / (NVOX/64);
  const int v0 = (tileIdx % (NVOX/64)) * 64;
  const int tid = (int)threadIdx.x;
  const int lane = tid & 63;
  const int wv   = tid >> 6;                 // wave id 0..3

  // 64 voxels = 2 aligned bitmap words (v0 multiple of 64)
  const int gbase = b*NVOX + v0;
  const unsigned int w0 = bitmap[(gbase >> 5)    ];
  const unsigned int w1 = bitmap[(gbase >> 5) + 1];

  if ((w0 | w1) == 0u) {
    // fully-untouched tile: write zeros directly, no LDS, no scratch reads
    float4 z; z.x=0.f; z.y=0.f; z.z=0.f; z.w=0.f;
    #pragma unroll
    for (int i=0; i<4; i++){
      const int idx = i*256 + tid;           // 0..1023
      const int cc  = idx >> 4;              // channel 0..63
      const int col = idx & 15;              // float4 col 0..15
      ((float4*)(out + ((size_t)b*NC + cc)*NVOX + v0))[col] = z;
    }
    return;
  }

  const unsigned long long bits =
      (unsigned long long)w0 | ((unsigned long long)w1 << 32);
  const float* src = scratch + ((size_t)gbase << 6);
  #pragma unroll
  for (int i=0; i<16; i++){
    const int r = wv*16 + i;                 // voxel row in tile
    tile[r][lane] = ((bits >> r) & 1ull) ? src[((size_t)r << 6) + lane] : 0.0f;
  }
  __syncthreads();
  float* dst = out + ((size_t)b*NC)*NVOX + v0;
  #pragma unroll
  for (int i=0; i<16; i++){
    const int cc = wv*16 + i;                // channel row
    dst[(size_t)cc*NVOX + lane] = tile[lane][cc];
  }
}

// -------- fallback (small ws): direct atomics into out --------
__global__ __launch_bounds__(256) void lss_scatter_direct_kernel(
    const float* __restrict__ x_img, const double* __restrict__ ws,
    float* __restrict__ out)
{
  const int slab = blockIdx.x / 11;
  const int sub  = blockIdx.x % 11;
  const int t = sub*256 + (int)threadIdx.x;
  const int w = t >> 6;
  const int c = t & 63;
  const int b = slab / (NCAM*NDD);
  const int rem = slab % (NCAM*NDD);
  const int n = rem / NDD;
  const int d = rem % NDD;
  const int bn = b*NCAM + n;

  int myAddr = voxel_addr_for_lane(ws, bn, b, d, w, c);
  if (myAddr >= 0){
    const int v = myAddr - b*NVOX;
    myAddr = b*NC*NVOX + v;                  // + c*NVOX added below
  }
  if (__ballot(myAddr >= 0) == 0ull) return;

  const float* featbase = x_img + (size_t)(((size_t)bn*NDD + d)*FHH*FWW)*NC
                        + ((size_t)w << 6) + c;
  float f[FHH];
  #pragma unroll
  for (int h=0; h<FHH; h++)
    f[h] = featbase[(size_t)h * (FWW*NC)];

  const int cOff = c * NVOX;
  int prevAddr = -1;
  float acc = 0.0f;
  #pragma unroll
  for (int h=0; h<FHH; h++){
    const int a = __shfl(myAddr, h, 64);
    const int addr = (a >= 0) ? (a + cOff) : -1;
    if (addr != prevAddr){
      if (prevAddr >= 0) atomicAdd(out + prevAddr, acc);
      acc = 0.0f;
      prevAddr = addr;
    }
    if (addr >= 0) acc += f[h];
  }
  if (prevAddr >= 0) atomicAdd(out + prevAddr, acc);
}

extern "C" void kernel_launch(void* const* d_in, const int* in_sizes, int n_in,
                              void* d_out, int out_size, void* d_ws, size_t ws_size,
                              hipStream_t stream) {
  const float* x_img      = (const float*)d_in[0];
  const float* rots       = (const float*)d_in[1];
  const float* trans      = (const float*)d_in[2];
  const float* intrins    = (const float*)d_in[3];
  const float* post_rots  = (const float*)d_in[4];
  const float* post_trans = (const float*)d_in[5];
  float* out = (float*)d_out;
  double* ws = (double*)d_ws;

  const size_t scratch_bytes = (size_t)NB * NVOX * NC * sizeof(float); // 40.96 MB
  const bool use_cf = ws_size >= SCRATCH_OFF_BYTES + scratch_bytes;

  if (use_cf) {
    unsigned int* bitmap = (unsigned int*)((char*)d_ws + BITMAP_OFF_BYTES);
    float* scratch = (float*)((char*)d_ws + SCRATCH_OFF_BYTES);
    lss_init_kernel<<<dim3(ZERO_BLOCKS + 21), dim3(256), 0, stream>>>(
        rots, intrins, post_rots, trans, post_trans, scratch, bitmap, ws);
    lss_scatter_cf_kernel<<<dim3(SCATTER_BLOCKS), dim3(256), 0, stream>>>(
        x_img, ws, scratch, bitmap);
    lss_transpose_kernel<<<dim3(NB*(NVOX/64)), dim3(256), 0, stream>>>(
        scratch, bitmap, out);
  } else {
    hipMemsetAsync(out, 0, (size_t)out_size * sizeof(float), stream);
    lss_precompute_kernel<<<1, 64, 0, stream>>>(rots, intrins, post_rots,
                                                trans, post_trans, ws);
    lss_scatter_direct_kernel<<<dim3(NB*NCAM*NDD*11), dim3(256), 0, stream>>>(x_img, ws, out);
  }
}